// Round 11
// baseline (593.534 us; speedup 1.0000x reference)
//
#include <hip/hip_runtime.h>
#include <math.h>

// RBF mixture: out[i] = sum_m w_m * exp(-(x_i-mu_m)^T C_m (x_i-mu_m)), C_m = G_m G_m^T
// N=32768, M=2048, D=32.
// Round 11: MX-fp8 screen. Quadratic-form GEMM in e4m3 via
// mfma_scale_f32_16x16x128_f8f6f4 (K=640 pad, 5 ksteps): ~2x bf16 pipe rate,
// half the B/LDS bytes, 128 arch regs freed (no spill). c-term dropped from
// the GEMM -- screen against th_m = SCREEN - c_m (survivors recompute exact
// fp32 anyway). Per-row e8m0 scale on B (unit scale on A). SCREEN=160 for
// fp8 error margin. Fallback list processing fused into survivor2.

#define NN 32768
#define MM 2048
#define DDIM 32
#define KQ 640             // fp8 K: 528 tri + 32 cross + 80 zero pad = 5*128
#define ROWS 128           // i-rows per screen block
#define KSTEPS 5
#define SCREEN 160.0f
#define MCAP 2048          // per-m survivor list capacity (ushort entries)
#define FCAP 1000000       // fallback flat list capacity
#define FBLK 64            // fallback blocks appended to survivor2 grid

typedef __attribute__((ext_vector_type(4))) float floatx4;
typedef __attribute__((ext_vector_type(8))) int int8v;

__device__ __forceinline__ unsigned int to_bf16(float f) {
  union { float f; unsigned int u; } x; x.f = f;
  return (x.u + 0x7fffu + ((x.u >> 16) & 1u)) >> 16;
}

// compile-time slot -> (d,f) table for the packed symmetric layout
struct DFTab { unsigned char d[528]; unsigned char f[528]; };
constexpr DFTab make_df() {
  DFTab t{};
  int s = 0;
  for (int d = 0; d < 32; ++d)
    for (int f = d; f < 32; ++f) {
      t.d[s] = (unsigned char)d; t.f[s] = (unsigned char)f; ++s;
    }
  return t;
}
constexpr DFTab DFT = make_df();

// value of A[row][s]; s must be compile-time. tri | cross(x_d) | zero pad
__device__ __forceinline__ float slot_val(const float* v, int s) {
  if (s < 528) return v[DFT.d[s]] * v[DFT.f[s]];
  if (s < 560) return v[s - 528];
  return 0.f;
}

// runtime slot -> (d,f) (build_b only)
__device__ __forceinline__ void slot_df(int s, int* dd, int* ff) {
  int d = 0, b = 0;
  while (b + (DDIM - d) <= s) { b += DDIM - d; ++d; }
  *dd = d; *ff = d + (s - b);
}

// ---------------------------------------------------------------------------
// Kernel 1: fp8 B-matrix [M][KQ] (e4m3, per-row e8m0 scale), sB[M] scale
// bytes, th[M] = SCREEN - mu^T C mu.
//  slots [0,528): C_dd diag / 2*C_df offdiag; [528,560): -2*(C mu); rest 0.
// ---------------------------------------------------------------------------
__global__ __launch_bounds__(256) void build_b_kernel(
    const float* __restrict__ gamma, const float* __restrict__ means,
    unsigned char* __restrict__ Bm8, unsigned char* __restrict__ sB,
    float* __restrict__ th) {
  __shared__ float G[DDIM][DDIM + 1];
  __shared__ float C[DDIM][DDIM + 1];
  __shared__ float bv[DDIM];
  __shared__ float cc;
  __shared__ float rmax[64];
  const int m = blockIdx.x;
  const int t = threadIdx.x;
  const float* g = gamma + (size_t)m * DDIM * DDIM;
  for (int l = t; l < DDIM * DDIM; l += 256) G[l >> 5][l & 31] = g[l];
  __syncthreads();
  const float* mu = means + m * DDIM;
  for (int l = t; l < DDIM * DDIM; l += 256) {
    int d = l >> 5, f = l & 31;
    float c = 0.f;
#pragma unroll
    for (int e = 0; e < DDIM; ++e) c += G[d][e] * G[f][e];
    C[d][f] = c;
  }
  __syncthreads();
  if (t < DDIM) {
    float b = 0.f;
#pragma unroll
    for (int f = 0; f < DDIM; ++f) b += C[t][f] * mu[f];
    bv[t] = b;
  }
  __syncthreads();
  if (t == 0) {
    float c = 0.f;
#pragma unroll
    for (int d = 0; d < DDIM; ++d) c += bv[d] * mu[d];
    cc = c;
  }
  // per-thread row values: thread t handles slots 4t..4t+3 (t < 140)
  float vals[4];
  float lmax = 0.f;
  __syncthreads();
  if (t < 140) {
#pragma unroll
    for (int q = 0; q < 4; ++q) {
      int s = t * 4 + q;
      float val;
      if (s < 528) {
        int d, f; slot_df(s, &d, &f);
        val = (d == f) ? C[d][d] : 2.f * C[d][f];
      } else if (s < 560) {
        val = -2.f * bv[s - 528];
      } else {
        val = 0.f;
      }
      vals[q] = val;
      lmax = fmaxf(lmax, fabsf(val));
    }
  }
  // reduce rowmax over 140 threads
  if (t < 64) rmax[t] = 0.f;
  __syncthreads();
  if (t < 140) {
    // wave-level max then LDS
    float wmax = lmax;
#pragma unroll
    for (int off = 32; off >= 1; off >>= 1)
      wmax = fmaxf(wmax, __shfl_down(wmax, off, 64));
    if ((t & 63) == 0) rmax[t >> 6] = wmax;
  }
  __syncthreads();
  __shared__ float sc_inv;
  __shared__ int sc_e;
  if (t == 0) {
    float rm = fmaxf(fmaxf(rmax[0], rmax[1]), fmaxf(rmax[2], rmax[3]));
    int e = 0;
    while (rm > 448.f * (float)(1 << e) && e < 16) ++e;
    sc_e = e;
    sc_inv = 1.f / (float)(1 << e);
    sB[m] = (unsigned char)(127 + e);
    th[m] = SCREEN - cc;
  }
  __syncthreads();
  if (t < 160) {
    unsigned int dw = 0;
    if (t < 140) {
      float si = sc_inv;
      int d0 = __builtin_amdgcn_cvt_pk_fp8_f32(vals[0] * si, vals[1] * si, 0, false);
      dw = (unsigned int)__builtin_amdgcn_cvt_pk_fp8_f32(vals[2] * si, vals[3] * si, d0, true);
    }
    *(unsigned int*)(Bm8 + (size_t)m * KQ + t * 4) = dw;
  }
}

// ---------------------------------------------------------------------------
// Exact scalar path (fallback list / shared by survivor kernels).
// ---------------------------------------------------------------------------
__device__ __noinline__ double survivor_contrib(
    int m, const float* __restrict__ gamma, const float* __restrict__ means,
    const float* __restrict__ weights, const float* __restrict__ xrow) {
  const float* mu = means + m * DDIM;
  float v[DDIM];
#pragma unroll
  for (int d = 0; d < DDIM; ++d) v[d] = xrow[d] - mu[d];
  const float* g = gamma + (size_t)m * DDIM * DDIM;
  float Dex = 0.f;
  for (int e = 0; e < DDIM; ++e) {
    float y = 0.f;
#pragma unroll
    for (int d = 0; d < DDIM; ++d) y += g[d * DDIM + e] * v[d];
    Dex += y * y;
  }
  float e2 = -Dex * 1.44269504088896340736f;
  float kf = floorf(e2);
  float mant = exp2f(e2 - kf);
  return ldexp((double)(weights[m] * mant), (int)kf);
}

// ---------------------------------------------------------------------------
// Kernel 2: MX-fp8 MFMA screen. 512 threads (8 waves), 128-row fp8 A-tile
// (80 KB dynamic LDS, XOR 16B-chunk swizzle), 1 block/CU, 2 waves/SIMD
// (launch_bounds(512,2) -> 256 regs/wave: 128 acc + ~70 arch, no spill).
// Per kstep (K=128): 8 B-loads (dwordx4) + per-row-tile 2 ds_read_b128 +
// 32 mfma_scale_16x16x128. A unit scale (0x7F), B per-row e8m0 scale.
// Screen: acc (= xCx - 2xb) < th[m] = SCREEN - c_m.
// A/B frag: lane holds row=lane&15, k=(lane>>4)*32..+31 (32 B = 8 VGPRs);
// C/D: col=lane&15, row=quad*4+reg (shape-determined, m121-m128).
// ---------------------------------------------------------------------------
__global__ __launch_bounds__(512, 2) void screen_kernel(
    const float* __restrict__ x, const unsigned char* __restrict__ Bm8,
    const unsigned char* __restrict__ sB, const float* __restrict__ th,
    unsigned int* __restrict__ mcnt, unsigned short* __restrict__ mlist,
    unsigned int* __restrict__ flist, unsigned int* __restrict__ fcount) {
  extern __shared__ __align__(16) unsigned char As[];    // ROWS * KQ bytes
  const int t = threadIdx.x;
  const int i0 = blockIdx.x * ROWS;
  const int lane = t & 63, w = t >> 6;                   // w in [0,8)
  const int lrow = lane & 15, quad = lane >> 4;
  const int rot = blockIdx.x & 31;

  // ---- generate fp8 A tile into swizzled LDS: row r (128), quarter j (4) ----
  {
    const int r = t >> 2, j = t & 3;                     // 10 chunks of 16B each
    float v[DDIM];
#pragma unroll
    for (int q = 0; q < 8; ++q)
      *(floatx4*)&v[q * 4] = *(const floatx4*)(x + (size_t)(i0 + r) * DDIM + q * 4);
#pragma unroll
    for (int jj = 0; jj < 4; ++jj) {
      if (j == jj) {
#pragma unroll
        for (int cc = 0; cc < 10; ++cc) {
          const int c = jj * 10 + cc;                    // chunk 0..39
          uint4 o;
          unsigned int dw[4];
#pragma unroll
          for (int q = 0; q < 4; ++q) {
            const int s0 = c * 16 + q * 4;
            int lo = __builtin_amdgcn_cvt_pk_fp8_f32(
                slot_val(v, s0 + 0), slot_val(v, s0 + 1), 0, false);
            dw[q] = (unsigned int)__builtin_amdgcn_cvt_pk_fp8_f32(
                slot_val(v, s0 + 2), slot_val(v, s0 + 3), lo, true);
          }
          o.x = dw[0]; o.y = dw[1]; o.z = dw[2]; o.w = dw[3];
          const int cs = (c & ~7) | ((c & 7) ^ (r & 7));
          *(uint4*)&As[(size_t)r * KQ + cs * 16] = o;
        }
      }
    }
  }
  __syncthreads();

#pragma unroll 1
  for (int g = 0; g < 4; ++g) {
    const int mq = ((g * 8 + w) + rot) & 31;            // rotated m-quad index
    const int m0 = mq * 64;
    const unsigned char* bp0 = Bm8 + (size_t)(m0 +  0 + lrow) * KQ + quad * 32;
    const unsigned char* bp1 = Bm8 + (size_t)(m0 + 16 + lrow) * KQ + quad * 32;
    const unsigned char* bp2 = Bm8 + (size_t)(m0 + 32 + lrow) * KQ + quad * 32;
    const unsigned char* bp3 = Bm8 + (size_t)(m0 + 48 + lrow) * KQ + quad * 32;
    // per-col-tile B row scales (byte replicated x4; opsel=0 reads byte 0)
    int sb0 = (int)sB[m0 +  0 + lrow] * 0x01010101;
    int sb1 = (int)sB[m0 + 16 + lrow] * 0x01010101;
    int sb2 = (int)sB[m0 + 32 + lrow] * 0x01010101;
    int sb3 = (int)sB[m0 + 48 + lrow] * 0x01010101;

    floatx4 acc[8][4] = {};                              // [ti][ct]
#pragma unroll
    for (int kk = 0; kk < KSTEPS; ++kk) {
      int8v bf[4];
#pragma unroll
      for (int ct = 0; ct < 4; ++ct) {
        const unsigned char* bp = (ct == 0) ? bp0 : (ct == 1) ? bp1
                                 : (ct == 2) ? bp2 : bp3;
        uint4 lo = *(const uint4*)(bp + kk * 128);
        uint4 hi = *(const uint4*)(bp + kk * 128 + 16);
        bf[ct][0] = lo.x; bf[ct][1] = lo.y; bf[ct][2] = lo.z; bf[ct][3] = lo.w;
        bf[ct][4] = hi.x; bf[ct][5] = hi.y; bf[ct][6] = hi.z; bf[ct][7] = hi.w;
      }
#pragma unroll
      for (int ti = 0; ti < 8; ++ti) {
        const int rr = ti * 16 + lrow;
        const int c0 = kk * 8 + quad * 2;
        const int cs0 = (c0 & ~7) | ((c0 & 7) ^ (rr & 7));
        const int c1 = c0 + 1;
        const int cs1 = (c1 & ~7) | ((c1 & 7) ^ (rr & 7));
        uint4 lo = *(const uint4*)&As[(size_t)rr * KQ + cs0 * 16];
        uint4 hi = *(const uint4*)&As[(size_t)rr * KQ + cs1 * 16];
        int8v af;
        af[0] = lo.x; af[1] = lo.y; af[2] = lo.z; af[3] = lo.w;
        af[4] = hi.x; af[5] = hi.y; af[6] = hi.z; af[7] = hi.w;
        acc[ti][0] = __builtin_amdgcn_mfma_scale_f32_16x16x128_f8f6f4(
            af, bf[0], acc[ti][0], 0, 0, 0, 0x7F7F7F7F, 0, sb0);
        acc[ti][1] = __builtin_amdgcn_mfma_scale_f32_16x16x128_f8f6f4(
            af, bf[1], acc[ti][1], 0, 0, 0, 0x7F7F7F7F, 0, sb1);
        acc[ti][2] = __builtin_amdgcn_mfma_scale_f32_16x16x128_f8f6f4(
            af, bf[2], acc[ti][2], 0, 0, 0, 0x7F7F7F7F, 0, sb2);
        acc[ti][3] = __builtin_amdgcn_mfma_scale_f32_16x16x128_f8f6f4(
            af, bf[3], acc[ti][3], 0, 0, 0, 0x7F7F7F7F, 0, sb3);
      }
    }

    // screen & emit survivors: acc < th[m] (= SCREEN - c_m)
    const float th0 = th[m0 +  0 + lrow];
    const float th1 = th[m0 + 16 + lrow];
    const float th2 = th[m0 + 32 + lrow];
    const float th3 = th[m0 + 48 + lrow];
#pragma unroll
    for (int ti = 0; ti < 8; ++ti)
#pragma unroll
      for (int ct = 0; ct < 4; ++ct) {
        const float tht = (ct == 0) ? th0 : (ct == 1) ? th1
                          : (ct == 2) ? th2 : th3;
#pragma unroll
        for (int r = 0; r < 4; ++r) {
          float Dt = acc[ti][ct][r];
          if (Dt < tht) {
            int gi = i0 + ti * 16 + quad * 4 + r;
            int gm = m0 + ct * 16 + lrow;
            unsigned int idx = atomicAdd(&mcnt[gm], 1u);
            if (idx < MCAP) {
              mlist[(size_t)gm * MCAP + idx] = (unsigned short)gi;
            } else {
              unsigned int fi = atomicAdd(fcount, 1u);
              if (fi < FCAP)
                flist[fi] = ((unsigned int)gi << 11) | (unsigned int)gm;
            }
          }
        }
      }
  }
}

// ---------------------------------------------------------------------------
// Kernel 3: survivor processing. Blocks [0,MM): per-m buckets with G_m^T in
// LDS. Blocks [MM,MM+FBLK): flat fallback list. Exact fp32 D; exp2f+ldexp.
// ---------------------------------------------------------------------------
__global__ __launch_bounds__(256) void survivor2_kernel(
    const unsigned int* __restrict__ mcnt, const unsigned short* __restrict__ mlist,
    const unsigned int* __restrict__ flist, const unsigned int* __restrict__ fcount,
    const float* __restrict__ x, const float* __restrict__ gamma,
    const float* __restrict__ means, const float* __restrict__ weights,
    double* __restrict__ acc_out) {
  const int blk = blockIdx.x;
  const int t = threadIdx.x;
  if (blk >= MM) {                                       // fallback path
    unsigned int total = *fcount;
    if (total > FCAP) total = FCAP;
    for (unsigned int idx = (blk - MM) * 256 + t; idx < total; idx += FBLK * 256) {
      unsigned int p = flist[idx];
      int gi = (int)(p >> 11), gm = (int)(p & 2047u);
      double c = survivor_contrib(gm, gamma, means, weights, x + (size_t)gi * DDIM);
      atomicAdd(&acc_out[gi], c);
    }
    return;
  }
  __shared__ float Gt[DDIM][DDIM + 1];   // Gt[e][d] = G[d][e]
  __shared__ float mu[DDIM];
  const int m = blk;
  unsigned int cnt = mcnt[m];
  if (cnt > MCAP) cnt = MCAP;
  if (cnt == 0) return;
  const float* g = gamma + (size_t)m * DDIM * DDIM;
  for (int l = t; l < DDIM * DDIM; l += 256) Gt[l & 31][l >> 5] = g[l];
  if (t < DDIM) mu[t] = means[m * DDIM + t];
  __syncthreads();
  const float wm = weights[m];
  for (unsigned int s = t; s < cnt; s += 256) {
    int gi = mlist[(size_t)m * MCAP + s];
    float v[DDIM];
#pragma unroll
    for (int q = 0; q < 8; ++q) {
      floatx4 xv = *(const floatx4*)(x + (size_t)gi * DDIM + q * 4);
      v[q * 4 + 0] = xv.x - mu[q * 4 + 0];
      v[q * 4 + 1] = xv.y - mu[q * 4 + 1];
      v[q * 4 + 2] = xv.z - mu[q * 4 + 2];
      v[q * 4 + 3] = xv.w - mu[q * 4 + 3];
    }
    float Dex = 0.f;
#pragma unroll
    for (int e = 0; e < DDIM; ++e) {
      float y = 0.f;
#pragma unroll
      for (int d = 0; d < DDIM; ++d) y += Gt[e][d] * v[d];
      Dex += y * y;
    }
    float e2 = -Dex * 1.44269504088896340736f;
    float kf = floorf(e2);
    float mant = exp2f(e2 - kf);
    atomicAdd(&acc_out[gi], ldexp((double)(wm * mant), (int)kf));
  }
}

__global__ __launch_bounds__(256) void finalize_kernel(
    const double* __restrict__ acc, float* __restrict__ out) {
  int i = blockIdx.x * 256 + threadIdx.x;
  out[i] = (float)acc[i];
}

extern "C" void kernel_launch(void* const* d_in, const int* in_sizes, int n_in,
                              void* d_out, int out_size, void* d_ws, size_t ws_size,
                              hipStream_t stream) {
  (void)in_sizes; (void)n_in; (void)out_size;
  const float* x       = (const float*)d_in[0];   // [N][32]
  const float* gamma   = (const float*)d_in[1];   // [M][32][32]
  const float* means   = (const float*)d_in[2];   // [M][32]
  const float* weights = (const float*)d_in[3];   // [M]

  char* p = (char*)d_ws;
  double* acc          = (double*)p;            p += (size_t)NN * 8;       // zeroed
  unsigned int* fcount = (unsigned int*)p;      p += 16;                   // zeroed
  unsigned int* mcnt   = (unsigned int*)p;      p += (size_t)MM * 4;       // zeroed
  unsigned short* mlist= (unsigned short*)p;    p += (size_t)MM * MCAP * 2;
  unsigned int* flist  = (unsigned int*)p;      p += (size_t)FCAP * 4;
  unsigned char* Bm8   = (unsigned char*)p;     p += (size_t)MM * KQ;
  unsigned char* sB    = (unsigned char*)p;     p += (size_t)MM;
  p = (char*)(((uintptr_t)p + 15) & ~(uintptr_t)15);
  float* th            = (float*)p;             p += (size_t)MM * 4;
  const size_t needed = (size_t)(p - (char*)d_ws);
  const size_t zero_bytes = (size_t)NN * 8 + 16 + (size_t)MM * 4;
  if (ws_size < needed) return;

  (void)hipFuncSetAttribute((const void*)screen_kernel,
                            hipFuncAttributeMaxDynamicSharedMemorySize,
                            ROWS * KQ);

  hipMemsetAsync(d_ws, 0, zero_bytes, stream);   // acc + fcount + mcnt
  hipLaunchKernelGGL(build_b_kernel, dim3(MM), dim3(256), 0, stream,
                     gamma, means, Bm8, sB, th);
  hipLaunchKernelGGL(screen_kernel, dim3(NN / ROWS), dim3(512),
                     ROWS * KQ, stream,
                     x, Bm8, sB, th, mcnt, mlist, flist, fcount);
  hipLaunchKernelGGL(survivor2_kernel, dim3(MM + FBLK), dim3(256), 0, stream,
                     mcnt, mlist, flist, fcount, x, gamma, means, weights, acc);
  hipLaunchKernelGGL(finalize_kernel, dim3(NN / 256), dim3(256), 0, stream,
                     acc, (float*)d_out);
}

// Round 12
// 185.079 us; speedup vs baseline: 3.2069x; 3.2069x over previous
//
#include <hip/hip_runtime.h>
#include <math.h>

// RBF mixture: out[i] = sum_m w_m * exp(-(x_i-mu_m)^T C_m (x_i-mu_m)), C_m = G_m G_m^T
// N=32768, M=2048, D=32.
// Round 12: r10 structure (bf16 screen, ROWS=128, 512 thr, 147 KB LDS A-tile,
// 32 MFMA/kstep) with launch_bounds(512,1): occupancy is LDS-bound (1 blk/CU,
// 2 waves/SIMD) regardless, so the 512-reg budget kills r10's 9.7 MB scratch
// spill for free and lets the compiler hoist B-loads. Fallback list fused
// into survivor2. (r11's MX-fp8 detour: spill + bank-alias catastrophe.)

#define NN 32768
#define MM 2048
#define DDIM 32
#define KSYM 576           // 528 triangle + 32 cross + 2 const + 14 pad = 18*32
#define ROWS 128           // i-rows per screen block
#define KSTEPS 18
#define SCREEN 120.0f
#define MCAP 2048          // per-m survivor list capacity (ushort entries)
#define FCAP 1000000       // fallback flat list capacity
#define FBLK 64            // fallback blocks appended to survivor2 grid

typedef __attribute__((ext_vector_type(8))) short short8;
typedef __attribute__((ext_vector_type(4))) float floatx4;

__device__ __forceinline__ unsigned int to_bf16(float f) {
  union { float f; unsigned int u; } x; x.f = f;
  return (x.u + 0x7fffu + ((x.u >> 16) & 1u)) >> 16;   // RNE, finite inputs only
}

// compile-time slot -> (d,f) table for the packed symmetric layout
struct DFTab { unsigned char d[528]; unsigned char f[528]; };
constexpr DFTab make_df() {
  DFTab t{};
  int s = 0;
  for (int d = 0; d < 32; ++d)
    for (int f = d; f < 32; ++f) {
      t.d[s] = (unsigned char)d; t.f[s] = (unsigned char)f; ++s;
    }
  return t;
}
constexpr DFTab DFT = make_df();

// value of A[row][s] given the row's x values; s must be compile-time
__device__ __forceinline__ float slot_val(const float* v, int s) {
  if (s < 528) return v[DFT.d[s]] * v[DFT.f[s]];
  if (s < 560) return v[s - 528];
  if (s < 562) return 1.f;
  return 0.f;
}

// runtime slot -> (d,f) (build_b only)
__device__ __forceinline__ void slot_df(int s, int* dd, int* ff) {
  int d = 0, b = 0;
  while (b + (DDIM - d) <= s) { b += DDIM - d; ++d; }
  *dd = d; *ff = d + (s - b);
}

// ---------------------------------------------------------------------------
// Kernel 1: bf16 B-matrix [M][KSYM]:
//  [0,528): C_dd diag / 2*C_df offdiag (triangle, d-major); [528,560): -2*(C mu);
//  560: c_hi, 561: c_lo (c = mu^T C mu); [562,576): 0
// ---------------------------------------------------------------------------
__global__ __launch_bounds__(256) void build_b_kernel(
    const float* __restrict__ gamma, const float* __restrict__ means,
    unsigned short* __restrict__ Bm) {
  __shared__ float G[DDIM][DDIM + 1];
  __shared__ float C[DDIM][DDIM + 1];
  __shared__ float bv[DDIM];
  __shared__ float cc;
  const int m = blockIdx.x;
  const int t = threadIdx.x;
  const float* g = gamma + (size_t)m * DDIM * DDIM;
  for (int l = t; l < DDIM * DDIM; l += 256) G[l >> 5][l & 31] = g[l];
  __syncthreads();
  const float* mu = means + m * DDIM;
  for (int l = t; l < DDIM * DDIM; l += 256) {
    int d = l >> 5, f = l & 31;
    float c = 0.f;
#pragma unroll
    for (int e = 0; e < DDIM; ++e) c += G[d][e] * G[f][e];
    C[d][f] = c;
  }
  __syncthreads();
  if (t < DDIM) {
    float b = 0.f;
#pragma unroll
    for (int f = 0; f < DDIM; ++f) b += C[t][f] * mu[f];
    bv[t] = b;
  }
  __syncthreads();
  if (t == 0) {
    float c = 0.f;
#pragma unroll
    for (int d = 0; d < DDIM; ++d) c += bv[d] * mu[d];
    cc = c;
  }
  __syncthreads();
  unsigned short* brow = Bm + (size_t)m * KSYM;
  for (int s = t; s < KSYM; s += 256) {
    float val;
    if (s < 528) {
      int d, f; slot_df(s, &d, &f);
      val = (d == f) ? C[d][d] : 2.f * C[d][f];
    } else if (s < 560) {
      val = -2.f * bv[s - 528];
    } else if (s == 560) {
      val = cc;
    } else if (s == 561) {
      unsigned int hi = to_bf16(cc);
      union { unsigned int u; float f; } xh; xh.u = hi << 16;
      val = cc - xh.f;
    } else {
      val = 0.f;
    }
    brow[s] = (unsigned short)to_bf16(val);
  }
}

// ---------------------------------------------------------------------------
// Exact scalar path (fallback list only).
// ---------------------------------------------------------------------------
__device__ __noinline__ double survivor_contrib(
    int m, const float* __restrict__ gamma, const float* __restrict__ means,
    const float* __restrict__ weights, const float* __restrict__ xrow) {
  const float* mu = means + m * DDIM;
  float v[DDIM];
#pragma unroll
  for (int d = 0; d < DDIM; ++d) v[d] = xrow[d] - mu[d];
  const float* g = gamma + (size_t)m * DDIM * DDIM;
  float Dex = 0.f;
  for (int e = 0; e < DDIM; ++e) {
    float y = 0.f;
#pragma unroll
    for (int d = 0; d < DDIM; ++d) y += g[d * DDIM + e] * v[d];
    Dex += y * y;
  }
  float e2 = -Dex * 1.44269504088896340736f;
  float kf = floorf(e2);
  float mant = exp2f(e2 - kf);
  return ldexp((double)(weights[m] * mant), (int)kf);
}

// ---------------------------------------------------------------------------
// Kernel 2: bf16 MFMA screen. 512 threads (8 waves), 128-row A-tile generated
// in-kernel into 147 KB dynamic LDS (XOR chunk swizzle; 0 conflicts r3-r10).
// Occupancy is LDS-bound: 1 block/CU, 2 waves/SIMD. launch_bounds(512,1)
// gives the 512-reg budget -> acc[8][4] + af[8] + bf[4] + hoisted B loads
// with NO scratch spill (r10 spilled 9.7 MB at the 256 cap).
// Per kstep: 4 B-loads + 8 ds_reads + 32 MFMA.
// Wave w sweeps m-quads ((g*8+w)+rot)&31, g=0..3, rot=blockIdx&31 (L2 spread).
// Frag layout (m89/m97): A/B [row=lane&15][k=quad*8+j]; C/D col=lane&15,
// row=quad*4+reg. Survivors -> per-m bucket lists; overflow -> flat list.
// ---------------------------------------------------------------------------
__global__ __launch_bounds__(512, 1) void screen_kernel(
    const float* __restrict__ x, const unsigned short* __restrict__ Bm,
    unsigned int* __restrict__ mcnt, unsigned short* __restrict__ mlist,
    unsigned int* __restrict__ flist, unsigned int* __restrict__ fcount) {
  extern __shared__ __align__(16) unsigned short As[];   // ROWS * KSYM
  const int t = threadIdx.x;
  const int i0 = blockIdx.x * ROWS;
  const int lane = t & 63, w = t >> 6;                   // w in [0,8)
  const int lrow = lane & 15, quad = lane >> 4;
  const int rot = blockIdx.x & 31;

  // ---- generate A tile into swizzled LDS: row r (128), chunk-quarter j (4) ----
  {
    const int r = t >> 2, j = t & 3;
    float v[DDIM];
#pragma unroll
    for (int q = 0; q < 8; ++q)
      *(floatx4*)&v[q * 4] = *(const floatx4*)(x + (size_t)(i0 + r) * DDIM + q * 4);
#pragma unroll
    for (int jj = 0; jj < 4; ++jj) {
      if (j == jj) {
#pragma unroll
        for (int cc = 0; cc < 18; ++cc) {
          const int c = jj * 18 + cc;                    // 16B chunk index 0..71
          unsigned int uu[4];
#pragma unroll
          for (int q = 0; q < 4; ++q) {
            const int s0 = c * 8 + q * 2;
            uu[q] = to_bf16(slot_val(v, s0)) | (to_bf16(slot_val(v, s0 + 1)) << 16);
          }
          const int cs = (c & ~7) | ((c & 7) ^ (r & 7));
          uint4 o; o.x = uu[0]; o.y = uu[1]; o.z = uu[2]; o.w = uu[3];
          *(uint4*)&As[r * KSYM + cs * 8] = o;
        }
      }
    }
  }
  __syncthreads();

#pragma unroll 1
  for (int g = 0; g < 4; ++g) {
    const int mq = ((g * 8 + w) + rot) & 31;            // rotated m-quad index
    const int m0 = mq * 64;
    const unsigned short* bb0 = Bm + (size_t)(m0 +  0 + lrow) * KSYM + quad * 8;
    const unsigned short* bb1 = Bm + (size_t)(m0 + 16 + lrow) * KSYM + quad * 8;
    const unsigned short* bb2 = Bm + (size_t)(m0 + 32 + lrow) * KSYM + quad * 8;
    const unsigned short* bb3 = Bm + (size_t)(m0 + 48 + lrow) * KSYM + quad * 8;

    floatx4 acc[8][4] = {};                              // [ti][mj]
#pragma unroll
    for (int kk = 0; kk < KSTEPS; ++kk) {
      short8 bf[4];
      bf[0] = *(const short8*)(bb0 + kk * 32);
      bf[1] = *(const short8*)(bb1 + kk * 32);
      bf[2] = *(const short8*)(bb2 + kk * 32);
      bf[3] = *(const short8*)(bb3 + kk * 32);
      short8 af[8];
#pragma unroll
      for (int ti = 0; ti < 8; ++ti) {
        int rr = ti * 16 + lrow;
        int c = kk * 4 + quad;
        int cs = (c & ~7) | ((c & 7) ^ (rr & 7));
        af[ti] = *(const short8*)&As[rr * KSYM + cs * 8];
      }
#pragma unroll
      for (int ti = 0; ti < 8; ++ti)
#pragma unroll
        for (int mj = 0; mj < 4; ++mj)
          acc[ti][mj] = __builtin_amdgcn_mfma_f32_16x16x32_bf16(
              af[ti], bf[mj], acc[ti][mj], 0, 0, 0);
    }

    // screen & emit survivors (rare) into per-m buckets
#pragma unroll
    for (int ti = 0; ti < 8; ++ti)
#pragma unroll
      for (int mj = 0; mj < 4; ++mj)
#pragma unroll
        for (int r = 0; r < 4; ++r) {
          float Dt = acc[ti][mj][r];
          if (Dt < SCREEN) {
            int gi = i0 + ti * 16 + quad * 4 + r;
            int gm = m0 + mj * 16 + lrow;
            unsigned int idx = atomicAdd(&mcnt[gm], 1u);
            if (idx < MCAP) {
              mlist[(size_t)gm * MCAP + idx] = (unsigned short)gi;
            } else {
              unsigned int fi = atomicAdd(fcount, 1u);
              if (fi < FCAP)
                flist[fi] = ((unsigned int)gi << 11) | (unsigned int)gm;
            }
          }
        }
  }
}

// ---------------------------------------------------------------------------
// Kernel 3: survivor processing. Blocks [0,MM): per-m buckets with G_m^T in
// LDS (broadcast reads). Blocks [MM,MM+FBLK): flat fallback list.
// Exact fp32 D; exp via exp2f mantissa + ldexp into double.
// ---------------------------------------------------------------------------
__global__ __launch_bounds__(256) void survivor2_kernel(
    const unsigned int* __restrict__ mcnt, const unsigned short* __restrict__ mlist,
    const unsigned int* __restrict__ flist, const unsigned int* __restrict__ fcount,
    const float* __restrict__ x, const float* __restrict__ gamma,
    const float* __restrict__ means, const float* __restrict__ weights,
    double* __restrict__ acc_out) {
  const int blk = blockIdx.x;
  const int t = threadIdx.x;
  if (blk >= MM) {                                       // fallback path
    unsigned int total = *fcount;
    if (total > FCAP) total = FCAP;
    for (unsigned int idx = (blk - MM) * 256 + t; idx < total; idx += FBLK * 256) {
      unsigned int p = flist[idx];
      int gi = (int)(p >> 11), gm = (int)(p & 2047u);
      double c = survivor_contrib(gm, gamma, means, weights, x + (size_t)gi * DDIM);
      atomicAdd(&acc_out[gi], c);
    }
    return;
  }
  __shared__ float Gt[DDIM][DDIM + 1];   // Gt[e][d] = G[d][e]
  __shared__ float mu[DDIM];
  const int m = blk;
  unsigned int cnt = mcnt[m];
  if (cnt > MCAP) cnt = MCAP;
  if (cnt == 0) return;
  const float* g = gamma + (size_t)m * DDIM * DDIM;
  for (int l = t; l < DDIM * DDIM; l += 256) Gt[l & 31][l >> 5] = g[l];
  if (t < DDIM) mu[t] = means[m * DDIM + t];
  __syncthreads();
  const float wm = weights[m];
  for (unsigned int s = t; s < cnt; s += 256) {
    int gi = mlist[(size_t)m * MCAP + s];
    float v[DDIM];
#pragma unroll
    for (int q = 0; q < 8; ++q) {
      floatx4 xv = *(const floatx4*)(x + (size_t)gi * DDIM + q * 4);
      v[q * 4 + 0] = xv.x - mu[q * 4 + 0];
      v[q * 4 + 1] = xv.y - mu[q * 4 + 1];
      v[q * 4 + 2] = xv.z - mu[q * 4 + 2];
      v[q * 4 + 3] = xv.w - mu[q * 4 + 3];
    }
    float Dex = 0.f;
#pragma unroll
    for (int e = 0; e < DDIM; ++e) {
      float y = 0.f;
#pragma unroll
      for (int d = 0; d < DDIM; ++d) y += Gt[e][d] * v[d];
      Dex += y * y;
    }
    float e2 = -Dex * 1.44269504088896340736f;
    float kf = floorf(e2);
    float mant = exp2f(e2 - kf);
    atomicAdd(&acc_out[gi], ldexp((double)(wm * mant), (int)kf));
  }
}

__global__ __launch_bounds__(256) void finalize_kernel(
    const double* __restrict__ acc, float* __restrict__ out) {
  int i = blockIdx.x * 256 + threadIdx.x;
  out[i] = (float)acc[i];
}

extern "C" void kernel_launch(void* const* d_in, const int* in_sizes, int n_in,
                              void* d_out, int out_size, void* d_ws, size_t ws_size,
                              hipStream_t stream) {
  (void)in_sizes; (void)n_in; (void)out_size;
  const float* x       = (const float*)d_in[0];   // [N][32]
  const float* gamma   = (const float*)d_in[1];   // [M][32][32]
  const float* means   = (const float*)d_in[2];   // [M][32]
  const float* weights = (const float*)d_in[3];   // [M]

  char* p = (char*)d_ws;
  double* acc          = (double*)p;            p += (size_t)NN * 8;       // zeroed
  unsigned int* fcount = (unsigned int*)p;      p += 16;                   // zeroed
  unsigned int* mcnt   = (unsigned int*)p;      p += (size_t)MM * 4;       // zeroed
  unsigned short* mlist= (unsigned short*)p;    p += (size_t)MM * MCAP * 2;
  unsigned int* flist  = (unsigned int*)p;      p += (size_t)FCAP * 4;
  unsigned short* Bm   = (unsigned short*)p;    p += (size_t)MM * KSYM * 2;
  const size_t needed = (size_t)(p - (char*)d_ws);
  const size_t zero_bytes = (size_t)NN * 8 + 16 + (size_t)MM * 4;
  if (ws_size < needed) return;

  (void)hipFuncSetAttribute((const void*)screen_kernel,
                            hipFuncAttributeMaxDynamicSharedMemorySize,
                            ROWS * KSYM * 2);

  hipMemsetAsync(d_ws, 0, zero_bytes, stream);   // acc + fcount + mcnt
  hipLaunchKernelGGL(build_b_kernel, dim3(MM), dim3(256), 0, stream, gamma, means, Bm);
  hipLaunchKernelGGL(screen_kernel, dim3(NN / ROWS), dim3(512),
                     ROWS * KSYM * 2, stream,
                     x, Bm, mcnt, mlist, flist, fcount);
  hipLaunchKernelGGL(survivor2_kernel, dim3(MM + FBLK), dim3(256), 0, stream,
                     mcnt, mlist, flist, fcount, x, gamma, means, weights, acc);
  hipLaunchKernelGGL(finalize_kernel, dim3(NN / 256), dim3(256), 0, stream,
                     acc, (float*)d_out);
}